// Round 3
// baseline (177.155 us; speedup 1.0000x reference)
//
#include <hip/hip_runtime.h>
#include <math.h>

// Monotone cubic spline flow (neural spline flow, cubic variant).
// B*D = 2,097,152 elements, K = 8 bins.
// R3: latency-bound fix — 2 independent elements per thread (2x ILP at same
// occupancy; VGPR stays <=64 so 8 waves/SIMD retained). Critical path
// shortened: no softmax max-subtract (inputs ~N(0,1), exp safe in fp32);
// slopes provably > 0 (widths,heights >= MIN_BIN) so sign() terms fold away.

constexpr int K = 8;
constexpr int E = 2;            // elements per thread
constexpr float TAIL = 3.0f;
constexpr float MIN_BIN = 0.001f;
constexpr float SEARCH_EPS = 1e-6f;

__device__ __forceinline__ float rcpf(float v) {
    return __builtin_amdgcn_rcpf(v);   // v_rcp_f32, ~1 ulp
}

__global__ __launch_bounds__(256) void cbs_kernel(
    const float* __restrict__ x_,
    const float* __restrict__ w_,
    const float* __restrict__ h_,
    const float* __restrict__ dl_,
    const float* __restrict__ dr_,
    float* __restrict__ out,
    float* __restrict__ lad,
    int n)
{
    int base = blockIdx.x * (256 * E) + threadIdx.x;

    int   idx[E];
    bool  valid[E];
    float wr[E][K], hr[E][K], xv[E], dlv[E], drv[E];

    // ---- issue ALL global loads up front (both elements in flight) ----
    #pragma unroll
    for (int e = 0; e < E; e++) {
        int i = base + e * 256;
        valid[e] = (i < n);
        if (i >= n) i = n - 1;
        idx[e] = i;
        const float4* w4 = (const float4*)w_ + 2 * (size_t)i;
        const float4* h4 = (const float4*)h_ + 2 * (size_t)i;
        float4 wa = w4[0], wb = w4[1];
        float4 ha = h4[0], hb = h4[1];
        wr[e][0]=wa.x; wr[e][1]=wa.y; wr[e][2]=wa.z; wr[e][3]=wa.w;
        wr[e][4]=wb.x; wr[e][5]=wb.y; wr[e][6]=wb.z; wr[e][7]=wb.w;
        hr[e][0]=ha.x; hr[e][1]=ha.y; hr[e][2]=ha.z; hr[e][3]=ha.w;
        hr[e][4]=hb.x; hr[e][5]=hb.y; hr[e][6]=hb.z; hr[e][7]=hb.w;
        xv[e]  = x_[i];
        dlv[e] = dl_[i];
        drv[e] = dr_[i];
    }

    // ---- two independent pipelines, unrolled; scheduler interleaves ----
    #pragma unroll
    for (int e = 0; e < E; e++) {
        // softmax + min-bin affine: widths (no max-subtract; |w| < ~6)
        float sw = 0.0f;
        #pragma unroll
        for (int k = 0; k < K; k++) { wr[e][k] = __expf(wr[e][k]); sw += wr[e][k]; }
        float cs = (1.0f - MIN_BIN * K) * rcpf(sw);
        #pragma unroll
        for (int k = 0; k < K; k++) wr[e][k] = MIN_BIN + cs * wr[e][k];

        // softmax + min-bin affine: heights
        float sh = 0.0f;
        #pragma unroll
        for (int k = 0; k < K; k++) { hr[e][k] = __expf(hr[e][k]); sh += hr[e][k]; }
        float csh = (1.0f - MIN_BIN * K) * rcpf(sh);
        #pragma unroll
        for (int k = 0; k < K; k++) hr[e][k] = MIN_BIN + csh * hr[e][k];

        // cumulative knots
        float cw[K + 1]; cw[0] = 0.0f;
        #pragma unroll
        for (int k = 0; k < K; k++) cw[k + 1] = cw[k] + wr[e][k];
        float ch[K + 1]; ch[0] = 0.0f;
        #pragma unroll
        for (int k = 0; k < K; k++) ch[k + 1] = ch[k] + hr[e][k];

        // slopes (all > 0 since widths/heights >= MIN_BIN)
        float s[K];
        #pragma unroll
        for (int k = 0; k < K; k++) s[k] = hr[e][k] * rcpf(wr[e][k]);

        // derivatives at knots; interior: 2*min(m1, m2) with signs == +1
        float dv[K + 1];
        dv[0] = rcpf(1.0f + __expf(-dlv[e])) * 3.0f * s[0];
        dv[K] = rcpf(1.0f + __expf(-drv[e])) * 3.0f * s[K - 1];
        #pragma unroll
        for (int k = 0; k < K - 1; k++) {
            float two_m1 = 2.0f * fminf(s[k], s[k + 1]);
            float m2x = (wr[e][k + 1] * s[k] + wr[e][k] * s[k + 1])
                        * rcpf(wr[e][k] + wr[e][k + 1]);   // == 2 * m2
            dv[k + 1] = fminf(two_m1, m2x);
        }

        // normalized position & bin search
        float t = (xv[e] + TAIL) * (1.0f / (2.0f * TAIL));
        t = fminf(fmaxf(t, 0.0f), 1.0f);

        int bin = 0;
        #pragma unroll
        for (int j = 1; j < K; j++) bin += (t >= cw[j]) ? 1 : 0;
        bin += (t >= 1.0f + SEARCH_EPS) ? 1 : 0;   // last knot = 1 + eps
        if (bin > K - 1) bin = K - 1;

        // gather per-bin quantities
        float wk = wr[e][0], sk = s[0], d0 = dv[0], d1 = dv[1], lw = cw[0], dd = ch[0];
        #pragma unroll
        for (int k = 1; k < K; k++) {
            bool sel = (bin == k);
            wk = sel ? wr[e][k]  : wk;
            sk = sel ? s[k]      : sk;
            d0 = sel ? dv[k]     : d0;
            d1 = sel ? dv[k + 1] : d1;
            lw = sel ? cw[k]     : lw;
            dd = sel ? ch[k]     : dd;
        }

        float inv_wk = rcpf(wk);
        float ia = (d0 + d1 - 2.0f * sk) * inv_wk * inv_wk;
        float ib = (3.0f * sk - 2.0f * d0 - d1) * inv_wk;
        float ic = d0;

        float sx = t - lw;
        float out_s = ((ia * sx + ib) * sx + ic) * sx + dd;
        float der   = (3.0f * ia * sx + 2.0f * ib) * sx + ic;
        float lad_s = __logf(fabsf(der));   // + log(6) - log(6) == 0

        out_s = fminf(fmaxf(out_s, 0.0f), 1.0f) * (2.0f * TAIL) - TAIL;

        bool inside = (xv[e] >= -TAIL) && (xv[e] <= TAIL);
        if (valid[e]) {
            out[idx[e]] = inside ? out_s : xv[e];
            lad[idx[e]] = inside ? lad_s : 0.0f;
        }
    }
}

extern "C" void kernel_launch(void* const* d_in, const int* in_sizes, int n_in,
                              void* d_out, int out_size, void* d_ws, size_t ws_size,
                              hipStream_t stream) {
    const float* x  = (const float*)d_in[0];
    const float* w  = (const float*)d_in[1];
    const float* h  = (const float*)d_in[2];
    const float* dl = (const float*)d_in[3];
    const float* dr = (const float*)d_in[4];
    int n = in_sizes[0];               // 8192*256 = 2,097,152
    float* out = (float*)d_out;        // outputs, then logabsdet, concatenated
    float* lad = out + n;

    const int threads = 256;
    const int per_block = threads * E;
    const int blocks = (n + per_block - 1) / per_block;
    cbs_kernel<<<blocks, threads, 0, stream>>>(x, w, h, dl, dr, out, lad, n);
}